// Round 3
// baseline (629.953 us; speedup 1.0000x reference)
//
#include <hip/hip_runtime.h>
#include <stdint.h>

// Problem constants
#define BROWS 16384
#define FDIM  2048
#define NCLS  14
#define ADIM  64
#define NCAT  2176   // 2048 (W_proj) + 14 (W_fc) + 114 zero pad -> 17 tiles of 128
#define QKN   1792   // 2*C*D
#define CTS   132    // C-tile LDS stride (shorts): banks = 8*quad + (m>>1) -> 2-way only

typedef __attribute__((ext_vector_type(8))) short bhalf8_t;   // 8 bf16 (4 VGPRs)
typedef __attribute__((ext_vector_type(4))) float f32x4_t;    // MFMA C/D frag

__device__ __forceinline__ unsigned short f2bf(float f) {
  unsigned int u = __builtin_bit_cast(unsigned int, f);
  u += 0x7fffu + ((u >> 16) & 1u);      // RNE
  return (unsigned short)(u >> 16);
}
__device__ __forceinline__ float bf2f(unsigned short s) {
  return __builtin_bit_cast(float, (unsigned int)s << 16);
}

__device__ __forceinline__ void gl_lds16(const void* g, void* l) {
  __builtin_amdgcn_global_load_lds(
      (const __attribute__((address_space(1))) unsigned int*)g,
      (__attribute__((address_space(3))) unsigned int*)l, 16, 0, 0);
}

// ---------------- elementwise prep ----------------

// cast n8*8 floats -> bf16, 8 per thread
__global__ void cast8_bf16(const float* __restrict__ src,
                           unsigned short* __restrict__ dst, int n8) {
  int t = blockIdx.x * 256 + threadIdx.x;
  if (t >= n8) return;
  const float4* s = (const float4*)src + 2 * (size_t)t;
  float4 a = s[0], b = s[1];
  bhalf8_t o;
  o[0] = f2bf(a.x); o[1] = f2bf(a.y); o[2] = f2bf(a.z); o[3] = f2bf(a.w);
  o[4] = f2bf(b.x); o[5] = f2bf(b.y); o[6] = f2bf(b.z); o[7] = f2bf(b.w);
  *((bhalf8_t*)dst + t) = o;
}

// build concatenated weight [NCAT, FDIM] bf16: rows 0..2047 = W_proj, 2048..2061 = W_fc, rest 0
__global__ void build_wcat(const float* __restrict__ Wp, const float* __restrict__ Wf,
                           unsigned short* __restrict__ dst) {
  int row = blockIdx.x;            // [0, NCAT)
  int c8 = threadIdx.x * 8;        // 256*8 == 2048
  const float* src = nullptr;
  if (row < 2048) src = Wp + (size_t)row * FDIM + c8;
  else if (row < 2048 + NCLS) src = Wf + (size_t)(row - 2048) * FDIM + c8;
  bhalf8_t o = {0,0,0,0,0,0,0,0};
  if (src) {
    float4 a = *(const float4*)src, b = *(const float4*)(src + 4);
    o[0] = f2bf(a.x); o[1] = f2bf(a.y); o[2] = f2bf(a.z); o[3] = f2bf(a.w);
    o[4] = f2bf(b.x); o[5] = f2bf(b.y); o[6] = f2bf(b.z); o[7] = f2bf(b.w);
  }
  *(bhalf8_t*)(dst + (size_t)row * FDIM + c8) = o;
}

// ---------------- MFMA GEMM: bf16 out via LDS-staged coalesced epilogue ----------------
// 128x128 tile, BK=64, 256 threads (4 waves 2x2), 16x16x32 bf16 MFMA.
// K-loop LDS: row = 8 chunks of 16B; chunk at slot (chunk ^ (row&7)) -> conflict-free
// ds_read_b128 while keeping global_load_lds destinations contiguous.
// Epilogue: two 64-row phases staged through LDS (stride CTS), then bhalf8 (16B/lane)
// fully-coalesced global stores -> full 64B lines (fixes R2's 2x write amplification).
// MODE 0 (GEMM1): cols<2048 -> bf16 h (+bias bp) + BN sum/sumsq atomics;
//                 col-block 16 -> fp32 logits[B,16] (+bias bfc), direct store.
// MODE 1 (GEMM2): plain bf16 store.
template<int MODE>
__global__ __launch_bounds__(256) void gemm_bt(
    const unsigned short* __restrict__ A, const unsigned short* __restrict__ Bw,
    const float* __restrict__ bp, const float* __restrict__ bfc,
    unsigned short* __restrict__ Cb, float* __restrict__ logits,
    float* __restrict__ colsum, float* __restrict__ colsq,
    int K, int lda, int ldb, int ldc)
{
  __shared__ unsigned short smem[2][128 * 64];
  unsigned short* lA = smem[0];
  unsigned short* lB = smem[1];
  const int tid = threadIdx.x;
  const int lane = tid & 63, wv = tid >> 6;
  const int m = lane & 15, quad = lane >> 4;
  const size_t rowBase = (size_t)blockIdx.x * 128;
  const size_t colBase = (size_t)blockIdx.y * 128;
  const int m0 = (wv >> 1) * 64, n0 = (wv & 1) * 64;

  f32x4_t acc[4][4];
#pragma unroll
  for (int i = 0; i < 4; ++i)
#pragma unroll
    for (int j = 0; j < 4; ++j) acc[i][j] = (f32x4_t){0.f, 0.f, 0.f, 0.f};

  int sS[4];                 // 16B slot index in LDS tile
  size_t gA[4], gB[4];       // element offsets of the staged chunk
#pragma unroll
  for (int i = 0; i < 4; ++i) {
    int s = ((i * 4 + wv) << 6) + lane;   // [0,1024): 4 issues x 4 waves x 64 lanes
    int r = s >> 3, qp = s & 7;
    int q = qp ^ (r & 7);                 // global k-chunk held at slot qp
    sS[i] = s;
    gA[i] = (rowBase + r) * (size_t)lda + q * 8;
    gB[i] = (colBase + r) * (size_t)ldb + q * 8;
  }

  for (int kb = 0; kb < K; kb += 64) {
#pragma unroll
    for (int i = 0; i < 4; ++i) {
      gl_lds16(A + gA[i] + kb, &lA[sS[i] * 8]);
      gl_lds16(Bw + gB[i] + kb, &lB[sS[i] * 8]);
    }
    __syncthreads();   // drains vmcnt before barrier
#pragma unroll
    for (int ks = 0; ks < 2; ++ks) {
      const int qc = ks * 4 + quad;       // k-chunk this lane's fragment needs
      bhalf8_t af[4], bf[4];
#pragma unroll
      for (int mi = 0; mi < 4; ++mi) {
        int r = m0 + mi * 16 + m;
        af[mi] = *(const bhalf8_t*)&lA[(r * 8 + (qc ^ (r & 7))) * 8];
      }
#pragma unroll
      for (int ni = 0; ni < 4; ++ni) {
        int r = n0 + ni * 16 + m;
        bf[ni] = *(const bhalf8_t*)&lB[(r * 8 + (qc ^ (r & 7))) * 8];
      }
#pragma unroll
      for (int mi = 0; mi < 4; ++mi)
#pragma unroll
        for (int ni = 0; ni < 4; ++ni)
          acc[mi][ni] = __builtin_amdgcn_mfma_f32_16x16x32_bf16(af[mi], bf[ni], acc[mi][ni], 0, 0, 0);
    }
    __syncthreads();
  }

  // ---- epilogue ---- (C/D layout: col = lane&15, row = quad*4 + reg)
  if (MODE == 0 && colBase >= 2048) {
    // logits tile (block-uniform branch): rel cols 0..15 only, direct fp32 store
    if (n0 == 0) {
      float bv = (m < NCLS) ? bfc[m] : 0.f;
#pragma unroll
      for (int mi = 0; mi < 4; ++mi) {
        size_t grow = rowBase + m0 + mi * 16 + quad * 4;
#pragma unroll
        for (int r = 0; r < 4; ++r)
          logits[(grow + r) * 16 + m] = acc[mi][0][r] + bv;
      }
    }
    return;
  }

  if (MODE == 0) {
    // fold bias into acc, then BN sum/sumsq atomics (register-side)
#pragma unroll
    for (int ni = 0; ni < 4; ++ni) {
      int gcol = (int)colBase + n0 + ni * 16 + m;
      float bv = bp[gcol];
      float s = 0.f, q = 0.f;
#pragma unroll
      for (int mi = 0; mi < 4; ++mi)
#pragma unroll
        for (int r = 0; r < 4; ++r) {
          float v = acc[mi][ni][r] + bv;
          acc[mi][ni][r] = v;
          s += v; q += v * v;
        }
      // lanes m, m+16, m+32, m+48 share gcol (disjoint rows)
      s += __shfl_xor(s, 16, 64); s += __shfl_xor(s, 32, 64);
      q += __shfl_xor(q, 16, 64); q += __shfl_xor(q, 32, 64);
      if (quad == 0) { atomicAdd(&colsum[gcol], s); atomicAdd(&colsq[gcol], q); }
    }
  }

  // two-phase LDS-staged coalesced store (reuses lA region; 64 rows x CTS shorts)
  unsigned short* ct = lA;
  const int hwv = wv >> 1;   // which 64-row half this wave's acc belongs to
#pragma unroll
  for (int ph = 0; ph < 2; ++ph) {
    if (ph) __syncthreads();           // previous phase's reads done
    if (hwv == ph) {
#pragma unroll
      for (int mi = 0; mi < 4; ++mi)
#pragma unroll
        for (int ni = 0; ni < 4; ++ni) {
          int lr = mi * 16 + quad * 4;
          int col = n0 + ni * 16 + m;
#pragma unroll
          for (int r = 0; r < 4; ++r)
            ct[(lr + r) * CTS + col] = f2bf(acc[mi][ni][r]);
        }
    }
    __syncthreads();
#pragma unroll
    for (int p = 0; p < 4; ++p) {
      int lr = p * 16 + (tid >> 4);
      int c0 = (tid & 15) * 8;
      bhalf8_t v = *(const bhalf8_t*)&ct[lr * CTS + c0];
      *(bhalf8_t*)&Cb[(rowBase + ph * 64 + lr) * (size_t)ldc + colBase + c0] = v;
    }
  }
}

// ---------------- BatchNorm finalize+apply (fused, in-place on bf16 h) ----------------
__global__ void bn_apply(unsigned short* __restrict__ hb,
                         const float* __restrict__ cs, const float* __restrict__ cq,
                         const float* __restrict__ g, const float* __restrict__ bt) {
  int t = blockIdx.x * 256 + threadIdx.x;   // grid 16384 -> t < 4194304
  int row = t >> 8;
  int c8 = (t & 255) << 3;
  const float inv = 1.f / (float)BROWS;
  float sc[8], sh[8];
#pragma unroll
  for (int j = 0; j < 8; ++j) {
    int c = c8 + j;
    float mu = cs[c] * inv;
    float var = cq[c] * inv - mu * mu;
    float s = g[c] * rsqrtf(var + 1e-5f);
    sc[j] = s;
    sh[j] = bt[c] - mu * s;
  }
  unsigned short* p = hb + (size_t)row * FDIM + c8;
  bhalf8_t v = *(bhalf8_t*)p;
  bhalf8_t o;
#pragma unroll
  for (int j = 0; j < 8; ++j)
    o[j] = f2bf(fmaxf(bf2f((unsigned short)v[j]) * sc[j] + sh[j], 0.f));
  *(bhalf8_t*)p = o;
}

// ---------------- attention epilogue: one wave per row ----------------
// attn = q k^T (14x14, K=64) via 16x16 MFMA chain on bf16 qk; diag subtract,
// max-|.| normalize, corr = attn @ sigmoid(logits); out = logits + gamma*corr.
__global__ __launch_bounds__(256) void attn_ep(
    const unsigned short* __restrict__ qk, const float* __restrict__ logits,
    const float* __restrict__ gamma, float* __restrict__ out)
{
  const int lane = threadIdx.x & 63;
  const int wv = threadIdx.x >> 6;
  const int b = blockIdx.x * 4 + wv;
  const int m = lane & 15, quad = lane >> 4;
  const unsigned short* qrow = qk + (size_t)b * QKN;
  f32x4_t acc = (f32x4_t){0.f, 0.f, 0.f, 0.f};
#pragma unroll
  for (int ks = 0; ks < 2; ++ks) {
    bhalf8_t af = {0,0,0,0,0,0,0,0}, bf = {0,0,0,0,0,0,0,0};
    if (m < NCLS) {
      af = *(const bhalf8_t*)(qrow + m * 64 + ks * 32 + quad * 8);        // q[b][m][k..k+8)
      bf = *(const bhalf8_t*)(qrow + 896 + m * 64 + ks * 32 + quad * 8);  // k[b][m][k..k+8)
    }
    acc = __builtin_amdgcn_mfma_f32_16x16x32_bf16(af, bf, acc, 0, 0, 0);
  }
  // acc[r] = attn[c = quad*4+r][e = m]
  float logit_e = (m < NCLS) ? logits[(size_t)b * 16 + m] : 0.f;
  float sig = 1.f / (1.f + __expf(-logit_e));
  float corr[4];
#pragma unroll
  for (int r = 0; r < 4; ++r) {
    int c = quad * 4 + r;
    float diag = __shfl(acc[r], (lane & 48) + c, 64);  // attn[c][c] lives in same 16-lane group
    float a = acc[r] - diag;
    float av = (m < NCLS) ? fabsf(a) : 0.f;
    av = fmaxf(av, __shfl_xor(av, 1, 64));
    av = fmaxf(av, __shfl_xor(av, 2, 64));
    av = fmaxf(av, __shfl_xor(av, 4, 64));
    av = fmaxf(av, __shfl_xor(av, 8, 64));
    float v = (m < NCLS) ? (a / av) * sig : 0.f;
    v += __shfl_xor(v, 1, 64);
    v += __shfl_xor(v, 2, 64);
    v += __shfl_xor(v, 4, 64);
    v += __shfl_xor(v, 8, 64);
    corr[r] = v;
  }
  if (m == 0) {
#pragma unroll
    for (int r = 0; r < 4; ++r) {
      int c = quad * 4 + r;
      if (c < NCLS) {
        float lc = logits[(size_t)b * 16 + c];
        out[(size_t)b * NCLS + c] = lc + gamma[c] * corr[r];
      }
    }
  }
}

// ---------------- launch ----------------

extern "C" void kernel_launch(void* const* d_in, const int* in_sizes, int n_in,
                              void* d_out, int out_size, void* d_ws, size_t ws_size,
                              hipStream_t stream) {
  const float* features = (const float*)d_in[0];
  const float* W_proj   = (const float*)d_in[1];
  const float* b_proj   = (const float*)d_in[2];
  const float* bn_gamma = (const float*)d_in[3];
  const float* bn_beta  = (const float*)d_in[4];
  const float* W_qk     = (const float*)d_in[5];
  const float* gamma    = (const float*)d_in[6];
  const float* W_fc     = (const float*)d_in[7];
  const float* b_fc     = (const float*)d_in[8];
  float* out = (float*)d_out;

  char* ws = (char*)d_ws;
  unsigned short* featC   = (unsigned short*)ws;                  //  67,108,864 B
  unsigned short* hbuf    = (unsigned short*)(ws + 67108864);     //  67,108,864 B (bf16 h, in-place BN)
  unsigned short* WcatC   = (unsigned short*)(ws + 134217728);    //   8,912,896 B
  unsigned short* WqkC    = (unsigned short*)(ws + 143130624);    //   7,340,032 B
  unsigned short* qkC     = (unsigned short*)(ws + 150470656);    //  58,720,256 B (bf16 qk)
  float*          logitsB = (float*)(ws + 209190912);             //   1,048,576 B ([B,16] fp32)
  float*          colsum  = (float*)(ws + 210239488);             //       8,192 B
  float*          colsq   = (float*)(ws + 210247680);             //       8,192 B (total 210,255,872)

  // zero BN accumulators (colsum+colsq adjacent) before GEMM1's fused stats
  hipMemsetAsync(colsum, 0, 16384, stream);

  // prep casts
  cast8_bf16<<<16384, 256, 0, stream>>>(features, featC, (BROWS * FDIM) / 8);
  build_wcat<<<NCAT, 256, 0, stream>>>(W_proj, W_fc, WcatC);
  cast8_bf16<<<1792, 256, 0, stream>>>(W_qk, WqkC, (QKN * FDIM) / 8);

  // GEMM1: bf16 h[B,2048] (+bias, +BN stats atomics) and fp32 logits[B,16] (+bias)
  gemm_bt<0><<<dim3(BROWS / 128, NCAT / 128), 256, 0, stream>>>(
      featC, WcatC, b_proj, b_fc, hbuf, logitsB, colsum, colsq,
      FDIM, FDIM, FDIM, FDIM);

  // BN finalize+apply (relu), in-place on bf16 h
  bn_apply<<<16384, 256, 0, stream>>>(hbuf, colsum, colsq, bn_gamma, bn_beta);

  // GEMM2: bf16 qk[B,1792] = h @ W_qk^T
  gemm_bt<1><<<dim3(BROWS / 128, QKN / 128), 256, 0, stream>>>(
      hbuf, WqkC, nullptr, nullptr, qkC, nullptr, nullptr, nullptr,
      FDIM, FDIM, FDIM, QKN);

  // attention epilogue (one wave per row)
  attn_ep<<<BROWS / 4, 256, 0, stream>>>(qkC, logitsB, gamma, out);
}